// Round 18
// baseline (116.531 us; speedup 1.0000x reference)
//
#include <hip/hip_runtime.h>
#include <math.h>

#define B_   2
#define T_   2048
#define C_   1024
#define H_   16
#define HD_  64
#define WIN_ 512
#define BT_  (B_ * T_)

typedef __bf16 bf16x8 __attribute__((ext_vector_type(8)));
typedef float  f32x4  __attribute__((ext_vector_type(4)));
typedef unsigned int u32x2 __attribute__((ext_vector_type(2)));
typedef unsigned short u16x8 __attribute__((ext_vector_type(8)));

__device__ __forceinline__ f32x4 mfma16(bf16x8 a, bf16x8 b, f32x4 c) {
    return __builtin_amdgcn_mfma_f32_16x16x32_bf16(a, b, c, 0, 0, 0);
}
__device__ __forceinline__ unsigned short f2b(float f) {
    __bf16 h = (__bf16)f;
    unsigned short u;
    __builtin_memcpy(&u, &h, 2);
    return u;
}
__device__ __forceinline__ void async_copy16(__bf16* lds, const __bf16* g) {
    __builtin_amdgcn_global_load_lds(
        (const __attribute__((address_space(1))) void*)g,
        (__attribute__((address_space(3))) void*)lds,
        16, 0, 0);
}

#define TR16(dst, va, OFFLIT) \
    asm volatile("ds_read_b64_tr_b16 %0, %1 offset:" OFFLIT : "=v"(dst) : "v"(va))

__device__ __forceinline__ bf16x8 combine_tr(u32x2 a, u32x2 b) {
    union { unsigned u[4]; bf16x8 v; } x;
    x.u[0] = a[0]; x.u[1] = a[1]; x.u[2] = b[0]; x.u[3] = b[1];
    return x.v;
}

#define VMW(n) asm volatile("s_waitcnt vmcnt(" #n ")" ::: "memory")

// ---------------- merged prep: 3x f32->bf16 convert + RoPE table ----------
__global__ void prep_k(const float* __restrict__ x, const float* __restrict__ Wqkv,
                       const float* __restrict__ Wproj,
                       __bf16* __restrict__ xb, __bf16* __restrict__ Wqkvb,
                       __bf16* __restrict__ Wprojb,
                       float* __restrict__ cosT, float* __restrict__ sinT) {
    const int gid = blockIdx.x * 256 + threadIdx.x;
    const int N0 = BT_ * 1024 / 8;
    const int N1 = N0 + 3072 * 1024 / 8;
    const int N2 = N1 + 1024 * 1024 / 8;
    const int N3 = N2 + T_ * 32 / 8;
    if (gid < N2) {
        const float* src; __bf16* dst; int off;
        if (gid < N0)      { src = x;     dst = xb;     off = gid; }
        else if (gid < N1) { src = Wqkv;  dst = Wqkvb;  off = gid - N0; }
        else               { src = Wproj; dst = Wprojb; off = gid - N1; }
        float4 a = *(const float4*)&src[(size_t)off * 8];
        float4 b = *(const float4*)&src[(size_t)off * 8 + 4];
        bf16x8 o;
        o[0] = (__bf16)a.x; o[1] = (__bf16)a.y; o[2] = (__bf16)a.z; o[3] = (__bf16)a.w;
        o[4] = (__bf16)b.x; o[5] = (__bf16)b.y; o[6] = (__bf16)b.z; o[7] = (__bf16)b.w;
        *(bf16x8*)&dst[(size_t)off * 8] = o;
    } else if (gid < N3) {
        const int r = gid - N2;
        #pragma unroll
        for (int e = 0; e < 8; ++e) {
            int idx = r * 8 + e;
            int t = idx >> 5, j = idx & 31;
            float inv = powf(10000.0f, -(float)j / 32.0f);
            float f = (float)t * inv;
            cosT[idx] = cosf(f);
            sinT[idx] = sinf(f);
        }
    }
}

// ---------------- 128x128 3-stage counted-vmcnt bf16 GEMM (QKV + RoPE) -----
// Proven r7/r9 schedule + XCD-chunked 1D grid (768 = 8 XCD x 96; each chunk
// sweeps 4 full bm rows -> 2MB A-panel resident per XCD L2).
__global__ __launch_bounds__(256) void gemm_qkv_rope(
        const __bf16* __restrict__ A, const __bf16* __restrict__ Bm,
        __bf16* __restrict__ Cv, int M, int N, int K,
        const float* __restrict__ cosT, const float* __restrict__ sinT)
{
    __shared__ __bf16 sA[3][128 * 32];
    __shared__ __bf16 sB[3][128 * 32];
    const int tid  = threadIdx.x;
    const int w    = tid >> 6;
    const int lane = tid & 63;
    const int c    = lane & 15;
    const int g    = lane >> 4;

    const int nbx = N >> 7;                 // 24
    const int cpx = gridDim.x >> 3;         // 96
    const int bid = blockIdx.x;
    const int swz = (bid & 7) * cpx + (bid >> 3);
    const int bm0 = (swz / nbx) << 7;
    const int bn0 = (swz % nbx) << 7;
    const int wm0 = (w >> 1) * 64;
    const int wn0 = (w & 1) * 64;

    f32x4 acc[4][4] = {};

    auto stage = [&](int buf, int k0) {
        #pragma unroll
        for (int it = 0; it < 2; ++it) {
            int s   = it * 256 + tid;
            int row = s >> 2;
            int col = ((s & 3) ^ ((row >> 1) & 3)) * 8;
            async_copy16(&sA[buf][s * 8], &A[(size_t)(bm0 + row) * K + k0 + col]);
            async_copy16(&sB[buf][s * 8], &Bm[(size_t)(bn0 + row) * K + k0 + col]);
        }
    };

    const int NT = K >> 5;
    stage(0, 0);
    stage(1, 32);

    int cons = 0;
    for (int t = 0; t < NT; ++t) {
        if (t + 1 < NT) { VMW(4); } else { VMW(0); }
        __builtin_amdgcn_sched_barrier(0);
        __builtin_amdgcn_s_barrier();
        if (t + 2 < NT) {
            int fill = cons + 2; if (fill >= 3) fill -= 3;
            stage(fill, (t + 2) * 32);
        }
        const __bf16* cA = sA[cons];
        const __bf16* cB = sB[cons];
        bf16x8 af[4], bfr[4];
        #pragma unroll
        for (int m = 0; m < 4; ++m) {
            int r = wm0 + m * 16 + c;
            af[m] = *(const bf16x8*)&cA[r * 32 + ((g ^ ((r >> 1) & 3)) * 8)];
        }
        #pragma unroll
        for (int n = 0; n < 4; ++n) {
            int r = wn0 + n * 16 + c;
            bfr[n] = *(const bf16x8*)&cB[r * 32 + ((g ^ ((r >> 1) & 3)) * 8)];
        }
        __builtin_amdgcn_s_setprio(1);
        #pragma unroll
        for (int m = 0; m < 4; ++m)
            #pragma unroll
            for (int n = 0; n < 4; ++n)
                acc[m][n] = mfma16(af[m], bfr[n], acc[m][n]);
        __builtin_amdgcn_s_setprio(0);
        cons = (cons + 1 == 3) ? 0 : cons + 1;
    }

    // ---- epilogue: fused RoPE on cols < 2048 (q,k), bf16 store ----
    #pragma unroll
    for (int m = 0; m < 4; ++m) {
        #pragma unroll
        for (int r2 = 0; r2 < 4; ++r2) {
            const int row = bm0 + wm0 + m * 16 + g * 4 + r2;
            const int t = row & (T_ - 1);
            #pragma unroll
            for (int n = 0; n < 4; ++n) {
                const int cbase = bn0 + wn0 + n * 16;
                const int cc = cbase + c;
                float v = acc[m][n][r2];
                float outv;
                if (cbase < 2048) {              // q or k region (uniform branch)
                    float prt = __shfl_xor(v, 1);
                    int jj = (cc & 63) >> 1;
                    float cs = cosT[t * 32 + jj];
                    float sn = sinT[t * 32 + jj];
                    outv = (cc & 1) ? (v * cs + prt * sn) : (v * cs - prt * sn);
                } else {
                    outv = v;
                }
                Cv[(size_t)row * N + cc] = (__bf16)outv;
            }
        }
    }
}

// ---------------- 128x64 proj GEMM, 3-stage counted-vmcnt (f32 out + bias) -
// Halves convoy rounds per CU vs 64x64 (512 blocks x 32 rounds, each with
// 6 ds_reads feeding 8 MFMA per wave). LDS 3 x (8+4) KB = 36 KB -> 4
// blocks/CU residency >= 2 needed by the 512-block grid (r16 rule checked).
// Schedule identical to QKV: VMW(3) [3 loads/thread/stage] -> barrier ->
// stage(t+2) -> reads -> MFMA. Same swizzle as QKV.
__global__ __launch_bounds__(256) void gemm_proj(
        const __bf16* __restrict__ A, const __bf16* __restrict__ Bm,
        const float* __restrict__ bias, float* __restrict__ Cv,
        int M, int N, int K)
{
    __shared__ __bf16 sA[3][128 * 32];
    __shared__ __bf16 sB[3][64 * 32];
    const int tid  = threadIdx.x;
    const int w    = tid >> 6;
    const int lane = tid & 63;
    const int c    = lane & 15;
    const int g    = lane >> 4;

    const int nbx = N >> 6;                 // 16
    const int cpx = gridDim.x >> 3;         // 64
    const int bid = blockIdx.x;
    const int swz = (bid & 7) * cpx + (bid >> 3);
    const int bm0 = (swz / nbx) << 7;
    const int bn0 = (swz % nbx) << 6;
    const int wm0 = (w >> 1) * 64;          // 0 / 64
    const int wn0 = (w & 1) * 32;           // 0 / 32

    f32x4 acc[4][2] = {};

    auto stage = [&](int buf, int k0) {     // 3 loads/thread
        #pragma unroll
        for (int it = 0; it < 2; ++it) {    // A: 512 slots
            int s   = it * 256 + tid;
            int row = s >> 2;
            int col = ((s & 3) ^ ((row >> 1) & 3)) * 8;
            async_copy16(&sA[buf][s * 8], &A[(size_t)(bm0 + row) * K + k0 + col]);
        }
        {                                   // B: 256 slots
            int s   = tid;
            int row = s >> 2;
            int col = ((s & 3) ^ ((row >> 1) & 3)) * 8;
            async_copy16(&sB[buf][s * 8], &Bm[(size_t)(bn0 + row) * K + k0 + col]);
        }
    };

    const int NT = K >> 5;                  // 32
    stage(0, 0);
    stage(1, 32);

    int cons = 0;
    for (int t = 0; t < NT; ++t) {
        if (t + 1 < NT) { VMW(3); } else { VMW(0); }
        __builtin_amdgcn_sched_barrier(0);
        __builtin_amdgcn_s_barrier();
        if (t + 2 < NT) {
            int fill = cons + 2; if (fill >= 3) fill -= 3;
            stage(fill, (t + 2) * 32);
        }
        const __bf16* cA = sA[cons];
        const __bf16* cB = sB[cons];
        bf16x8 af[4], bfr[2];
        #pragma unroll
        for (int m = 0; m < 4; ++m) {
            int r = wm0 + m * 16 + c;
            af[m] = *(const bf16x8*)&cA[r * 32 + ((g ^ ((r >> 1) & 3)) * 8)];
        }
        #pragma unroll
        for (int n = 0; n < 2; ++n) {
            int r = wn0 + n * 16 + c;
            bfr[n] = *(const bf16x8*)&cB[r * 32 + ((g ^ ((r >> 1) & 3)) * 8)];
        }
        __builtin_amdgcn_s_setprio(1);
        #pragma unroll
        for (int m = 0; m < 4; ++m)
            #pragma unroll
            for (int n = 0; n < 2; ++n)
                acc[m][n] = mfma16(af[m], bfr[n], acc[m][n]);
        __builtin_amdgcn_s_setprio(0);
        cons = (cons + 1 == 3) ? 0 : cons + 1;
    }

    #pragma unroll
    for (int m = 0; m < 4; ++m) {
        int rr = bm0 + wm0 + m * 16 + g * 4;
        #pragma unroll
        for (int n = 0; n < 2; ++n) {
            int cc = bn0 + wn0 + n * 16 + c;
            float bv = bias[cc];
            #pragma unroll
            for (int r2 = 0; r2 < 4; ++r2)
                Cv[(size_t)(rr + r2) * N + cc] = acc[m][n][r2] + bv;
        }
    }
}

// ---------------- banded flash attention, KVBLK=32, K/V dbuf ---------------
// Last tile ends at j_end = q0+32 so keys q0+32..q0+63 reach the upper
// query rows; mask zeroes out-of-band entries. LDS ~26KB -> one dispatch
// round for all 1024 blocks.
__global__ __launch_bounds__(256) void attn_k(const __bf16* __restrict__ qkv,
                                              __bf16* __restrict__ y)
{
    __shared__ __align__(16) unsigned short Ks[2][32 * 72];
    __shared__ __align__(16) unsigned short Vs[2][4 * 528];
    __shared__ __align__(16) unsigned short Ps[64 * 72];

    const int tid  = threadIdx.x;
    const int lane = tid & 63;
    const int w    = tid >> 6;
    const int c    = lane & 15;
    const int g    = lane >> 4;

    const int bid = blockIdx.x;
    const int swz = (bid & 7) * 128 + (bid >> 3);
    const int q0 = (swz & 31) * 64;
    const int hb = swz >> 5;
    const int h  = hb & 15;
    const int b  = hb >> 4;

    bf16x8 qa[2];
    {
        const int qrow = q0 + w * 16 + c;
        const __bf16* qp = qkv + (size_t)(b * T_ + qrow) * 3072 + h * 64 + g * 8;
        bf16x8 r0 = *(const bf16x8*)qp;
        bf16x8 r1 = *(const bf16x8*)(qp + 32);
        #pragma unroll
        for (int e = 0; e < 8; ++e) {
            qa[0][e] = (__bf16)((float)r0[e] * 0.125f);
            qa[1][e] = (__bf16)((float)r1[e] * 0.125f);
        }
    }

    float m_run[4] = {-1e30f, -1e30f, -1e30f, -1e30f};
    float l_run[4] = {0.f, 0.f, 0.f, 0.f};
    f32x4 o[4] = {};

    unsigned vs_lane;
    {
        auto* p3 = (__attribute__((address_space(3))) const unsigned short*)&Vs[0][0];
        vs_lane = (unsigned)(unsigned long long)p3 + (unsigned)(g * 256 + c * 8);
    }

    const int rs = tid >> 3, d8 = (tid & 7) * 8;
    const size_t kbase = (size_t)(b * T_) * 3072 + 1024 + h * 64;

    const int j_start = (q0 >= WIN_) ? (q0 - WIN_) : 0;
    const int j_end   = q0 + 32;

    u16x8 kr, vr;
    {
        const __bf16* p0 = qkv + kbase + (size_t)(j_start + rs) * 3072 + d8;
        kr = *(const u16x8*)p0;  vr = *(const u16x8*)(p0 + 1024);
    }

    int cur = 0;
    for (int j0 = j_start; j0 <= j_end; j0 += 32) {
        *(u16x8*)&Ks[cur][rs * 72 + d8] = kr;
        *(u16x8*)&Vs[cur][(d8 >> 4) * 528 + rs * 16 + (d8 & 15)] = vr;
        __syncthreads();

        if (j0 + 32 <= j_end) {
            const __bf16* p0 = qkv + kbase + (size_t)(j0 + 32 + rs) * 3072 + d8;
            kr = *(const u16x8*)p0;  vr = *(const u16x8*)(p0 + 1024);
        }

        f32x4 sc[2];
        __builtin_amdgcn_s_setprio(1);
        #pragma unroll
        for (int nt = 0; nt < 2; ++nt) {
            const bf16x8 b0 = *(const bf16x8*)&Ks[cur][(nt * 16 + c) * 72 + g * 8];
            const bf16x8 b1 = *(const bf16x8*)&Ks[cur][(nt * 16 + c) * 72 + 32 + g * 8];
            f32x4 s = {0.f, 0.f, 0.f, 0.f};
            s = mfma16(qa[0], b0, s);
            s = mfma16(qa[1], b1, s);
            sc[nt] = s;
        }
        __builtin_amdgcn_s_setprio(0);

        const int rlo = q0 + w * 16;
        const bool need_mask = (j0 + 31 > rlo) || (rlo + 15 - j0 > WIN_);
        if (need_mask) {
            #pragma unroll
            for (int reg = 0; reg < 4; ++reg) {
                const int i_abs = rlo + g * 4 + reg;
                #pragma unroll
                for (int nt = 0; nt < 2; ++nt) {
                    int j_abs = j0 + nt * 16 + c;
                    bool ok = (j_abs <= i_abs) && (i_abs - j_abs <= WIN_);
                    sc[nt][reg] = ok ? sc[nt][reg] : -1e30f;
                }
            }
        }

        float pmax[4];
        #pragma unroll
        for (int reg = 0; reg < 4; ++reg) {
            float bm = fmaxf(sc[0][reg], sc[1][reg]);
            #pragma unroll
            for (int off = 1; off < 16; off <<= 1)
                bm = fmaxf(bm, __shfl_xor(bm, off));
            pmax[reg] = bm;
        }
        int need = 0;
        #pragma unroll
        for (int reg = 0; reg < 4; ++reg)
            need |= (pmax[reg] > m_run[reg] + 8.f) ? 1 : 0;
        if (__any(need)) {
            #pragma unroll
            for (int reg = 0; reg < 4; ++reg) {
                float mn = fmaxf(m_run[reg], pmax[reg]);
                float corr = __expf(m_run[reg] - mn);
                m_run[reg] = mn;
                l_run[reg] *= corr;
                #pragma unroll
                for (int dt = 0; dt < 4; ++dt) o[dt][reg] *= corr;
            }
        }
        #pragma unroll
        for (int reg = 0; reg < 4; ++reg) {
            #pragma unroll
            for (int nt = 0; nt < 2; ++nt) {
                float p = __expf(sc[nt][reg] - m_run[reg]);
                l_run[reg] += p;
                Ps[(w * 16 + g * 4 + reg) * 72 + nt * 16 + c] = f2b(p);
            }
        }

        const bf16x8 pa = *(const bf16x8*)&Ps[(w * 16 + c) * 72 + g * 8];
        u32x2 t0[4], t1[4];
        #pragma unroll
        for (int dt = 0; dt < 4; ++dt) {
            unsigned va = vs_lane + (unsigned)cur * 4224u + dt * 1056u;
            TR16(t0[dt], va, "0");
            TR16(t1[dt], va, "128");
        }
        asm volatile("s_waitcnt lgkmcnt(0)" ::: "memory");
        __builtin_amdgcn_sched_barrier(0);
        __builtin_amdgcn_s_setprio(1);
        #pragma unroll
        for (int dt = 0; dt < 4; ++dt) {
            bf16x8 vb = combine_tr(t0[dt], t1[dt]);
            o[dt] = mfma16(pa, vb, o[dt]);
        }
        __builtin_amdgcn_s_setprio(0);
        cur ^= 1;
    }

    float inv_l[4];
    #pragma unroll
    for (int reg = 0; reg < 4; ++reg) {
        float L = l_run[reg];
        #pragma unroll
        for (int off = 1; off < 16; off <<= 1)
            L += __shfl_xor(L, off);
        inv_l[reg] = 1.f / L;
    }
    #pragma unroll
    for (int dt = 0; dt < 4; ++dt)
        #pragma unroll
        for (int reg = 0; reg < 4; ++reg) {
            size_t row = (size_t)(b * T_ + q0 + w * 16 + g * 4 + reg);
            y[row * 1024 + h * 64 + dt * 16 + c] = (__bf16)(o[dt][reg] * inv_l[reg]);
        }
}

// ---------------- launch ----------------
extern "C" void kernel_launch(void* const* d_in, const int* in_sizes, int n_in,
                              void* d_out, int out_size, void* d_ws, size_t ws_size,
                              hipStream_t stream) {
    const float* x     = (const float*)d_in[0];
    const float* Wqkv  = (const float*)d_in[1];
    const float* Wproj = (const float*)d_in[2];
    const float* bproj = (const float*)d_in[3];
    float* out = (float*)d_out;

    char* p = (char*)d_ws;
    float*  cosT   = (float*)p;   p += (size_t)T_ * 32 * 4;
    float*  sinT   = (float*)p;   p += (size_t)T_ * 32 * 4;
    __bf16* xb     = (__bf16*)p;  p += (size_t)BT_ * 1024 * 2;
    __bf16* Wqkvb  = (__bf16*)p;  p += (size_t)3072 * 1024 * 2;
    __bf16* Wprojb = (__bf16*)p;  p += (size_t)1024 * 1024 * 2;
    __bf16* qkvb   = (__bf16*)p;  p += (size_t)BT_ * 3072 * 2;
    __bf16* yb     = (__bf16*)p;  p += (size_t)BT_ * 1024 * 2;

    const int nprep = (BT_ * 1024 + 3072 * 1024 + 1024 * 1024) / 8 + T_ * 32 / 8;
    prep_k<<<(nprep + 255) / 256, 256, 0, stream>>>(
        x, Wqkv, Wproj, xb, Wqkvb, Wprojb, cosT, sinT);

    dim3 g1((BT_ / 128) * (3072 / 128));
    gemm_qkv_rope<<<g1, 256, 0, stream>>>(
        xb, Wqkvb, qkvb, BT_, 3072, 1024, cosT, sinT);

    attn_k<<<(T_ / 64) * H_ * B_, 256, 0, stream>>>(qkvb, yb);

    gemm_proj<<<(BT_ / 128) * (1024 / 64), 256, 0, stream>>>(
        yb, Wprojb, bproj, out, BT_, 1024, 1024);
}

// Round 19
// 114.402 us; speedup vs baseline: 1.0186x; 1.0186x over previous
//
#include <hip/hip_runtime.h>
#include <math.h>

#define B_   2
#define T_   2048
#define C_   1024
#define H_   16
#define HD_  64
#define WIN_ 512
#define BT_  (B_ * T_)

typedef __bf16 bf16x8 __attribute__((ext_vector_type(8)));
typedef float  f32x4  __attribute__((ext_vector_type(4)));
typedef unsigned int u32x2 __attribute__((ext_vector_type(2)));
typedef unsigned short u16x8 __attribute__((ext_vector_type(8)));

__device__ __forceinline__ f32x4 mfma16(bf16x8 a, bf16x8 b, f32x4 c) {
    return __builtin_amdgcn_mfma_f32_16x16x32_bf16(a, b, c, 0, 0, 0);
}
__device__ __forceinline__ unsigned short f2b(float f) {
    __bf16 h = (__bf16)f;
    unsigned short u;
    __builtin_memcpy(&u, &h, 2);
    return u;
}
__device__ __forceinline__ void async_copy16(__bf16* lds, const __bf16* g) {
    __builtin_amdgcn_global_load_lds(
        (const __attribute__((address_space(1))) void*)g,
        (__attribute__((address_space(3))) void*)lds,
        16, 0, 0);
}

#define TR16(dst, va, OFFLIT) \
    asm volatile("ds_read_b64_tr_b16 %0, %1 offset:" OFFLIT : "=v"(dst) : "v"(va))

__device__ __forceinline__ bf16x8 combine_tr(u32x2 a, u32x2 b) {
    union { unsigned u[4]; bf16x8 v; } x;
    x.u[0] = a[0]; x.u[1] = a[1]; x.u[2] = b[0]; x.u[3] = b[1];
    return x.v;
}

#define VMW(n) asm volatile("s_waitcnt vmcnt(" #n ")" ::: "memory")

// ---------------- merged prep: 3x f32->bf16 convert + RoPE table ----------
__global__ void prep_k(const float* __restrict__ x, const float* __restrict__ Wqkv,
                       const float* __restrict__ Wproj,
                       __bf16* __restrict__ xb, __bf16* __restrict__ Wqkvb,
                       __bf16* __restrict__ Wprojb,
                       float* __restrict__ cosT, float* __restrict__ sinT) {
    const int gid = blockIdx.x * 256 + threadIdx.x;
    const int N0 = BT_ * 1024 / 8;
    const int N1 = N0 + 3072 * 1024 / 8;
    const int N2 = N1 + 1024 * 1024 / 8;
    const int N3 = N2 + T_ * 32 / 8;
    if (gid < N2) {
        const float* src; __bf16* dst; int off;
        if (gid < N0)      { src = x;     dst = xb;     off = gid; }
        else if (gid < N1) { src = Wqkv;  dst = Wqkvb;  off = gid - N0; }
        else               { src = Wproj; dst = Wprojb; off = gid - N1; }
        float4 a = *(const float4*)&src[(size_t)off * 8];
        float4 b = *(const float4*)&src[(size_t)off * 8 + 4];
        bf16x8 o;
        o[0] = (__bf16)a.x; o[1] = (__bf16)a.y; o[2] = (__bf16)a.z; o[3] = (__bf16)a.w;
        o[4] = (__bf16)b.x; o[5] = (__bf16)b.y; o[6] = (__bf16)b.z; o[7] = (__bf16)b.w;
        *(bf16x8*)&dst[(size_t)off * 8] = o;
    } else if (gid < N3) {
        const int r = gid - N2;
        #pragma unroll
        for (int e = 0; e < 8; ++e) {
            int idx = r * 8 + e;
            int t = idx >> 5, j = idx & 31;
            float inv = powf(10000.0f, -(float)j / 32.0f);
            float f = (float)t * inv;
            cosT[idx] = cosf(f);
            sinT[idx] = sinf(f);
        }
    }
}

// ---------------- 128x128 3-stage counted-vmcnt bf16 GEMM (QKV + RoPE) -----
// Proven r7/r9 schedule + XCD-chunked 1D grid (768 = 8 XCD x 96; each chunk
// sweeps 4 full bm rows -> 2MB A-panel resident per XCD L2).
__global__ __launch_bounds__(256) void gemm_qkv_rope(
        const __bf16* __restrict__ A, const __bf16* __restrict__ Bm,
        __bf16* __restrict__ Cv, int M, int N, int K,
        const float* __restrict__ cosT, const float* __restrict__ sinT)
{
    __shared__ __bf16 sA[3][128 * 32];
    __shared__ __bf16 sB[3][128 * 32];
    const int tid  = threadIdx.x;
    const int w    = tid >> 6;
    const int lane = tid & 63;
    const int c    = lane & 15;
    const int g    = lane >> 4;

    const int nbx = N >> 7;                 // 24
    const int cpx = gridDim.x >> 3;         // 96
    const int bid = blockIdx.x;
    const int swz = (bid & 7) * cpx + (bid >> 3);
    const int bm0 = (swz / nbx) << 7;
    const int bn0 = (swz % nbx) << 7;
    const int wm0 = (w >> 1) * 64;
    const int wn0 = (w & 1) * 64;

    f32x4 acc[4][4] = {};

    auto stage = [&](int buf, int k0) {
        #pragma unroll
        for (int it = 0; it < 2; ++it) {
            int s   = it * 256 + tid;
            int row = s >> 2;
            int col = ((s & 3) ^ ((row >> 1) & 3)) * 8;
            async_copy16(&sA[buf][s * 8], &A[(size_t)(bm0 + row) * K + k0 + col]);
            async_copy16(&sB[buf][s * 8], &Bm[(size_t)(bn0 + row) * K + k0 + col]);
        }
    };

    const int NT = K >> 5;
    stage(0, 0);
    stage(1, 32);

    int cons = 0;
    for (int t = 0; t < NT; ++t) {
        if (t + 1 < NT) { VMW(4); } else { VMW(0); }
        __builtin_amdgcn_sched_barrier(0);
        __builtin_amdgcn_s_barrier();
        if (t + 2 < NT) {
            int fill = cons + 2; if (fill >= 3) fill -= 3;
            stage(fill, (t + 2) * 32);
        }
        const __bf16* cA = sA[cons];
        const __bf16* cB = sB[cons];
        bf16x8 af[4], bfr[4];
        #pragma unroll
        for (int m = 0; m < 4; ++m) {
            int r = wm0 + m * 16 + c;
            af[m] = *(const bf16x8*)&cA[r * 32 + ((g ^ ((r >> 1) & 3)) * 8)];
        }
        #pragma unroll
        for (int n = 0; n < 4; ++n) {
            int r = wn0 + n * 16 + c;
            bfr[n] = *(const bf16x8*)&cB[r * 32 + ((g ^ ((r >> 1) & 3)) * 8)];
        }
        __builtin_amdgcn_s_setprio(1);
        #pragma unroll
        for (int m = 0; m < 4; ++m)
            #pragma unroll
            for (int n = 0; n < 4; ++n)
                acc[m][n] = mfma16(af[m], bfr[n], acc[m][n]);
        __builtin_amdgcn_s_setprio(0);
        cons = (cons + 1 == 3) ? 0 : cons + 1;
    }

    // ---- epilogue: fused RoPE on cols < 2048 (q,k), bf16 store ----
    #pragma unroll
    for (int m = 0; m < 4; ++m) {
        #pragma unroll
        for (int r2 = 0; r2 < 4; ++r2) {
            const int row = bm0 + wm0 + m * 16 + g * 4 + r2;
            const int t = row & (T_ - 1);
            #pragma unroll
            for (int n = 0; n < 4; ++n) {
                const int cbase = bn0 + wn0 + n * 16;
                const int cc = cbase + c;
                float v = acc[m][n][r2];
                float outv;
                if (cbase < 2048) {              // q or k region (uniform branch)
                    float prt = __shfl_xor(v, 1);
                    int jj = (cc & 63) >> 1;
                    float cs = cosT[t * 32 + jj];
                    float sn = sinT[t * 32 + jj];
                    outv = (cc & 1) ? (v * cs + prt * sn) : (v * cs - prt * sn);
                } else {
                    outv = v;
                }
                Cv[(size_t)row * N + cc] = (__bf16)outv;
            }
        }
    }
}

// ---------------- 64x64 high-occupancy proj GEMM, BK=32 (f32 out + bias) ---
// 24KB LDS -> 6 blocks/CU residency >= 4 needed by the 1024-block grid.
// (r16: BK=64 regressed, residency 3 < 4; r18: 128x64 regressed, TLP loss.)
__global__ __launch_bounds__(256) void gemm64_proj(
        const __bf16* __restrict__ A, const __bf16* __restrict__ Bm,
        const float* __restrict__ bias, float* __restrict__ Cv,
        int M, int N, int K)
{
    __shared__ __bf16 sA[3][64 * 32];
    __shared__ __bf16 sB[3][64 * 32];
    const int tid  = threadIdx.x;
    const int w    = tid >> 6;
    const int lane = tid & 63;
    const int c    = lane & 15;
    const int g    = lane >> 4;

    const int nbx = N >> 6;                 // 16
    const int cpx = gridDim.x >> 3;
    const int bid = blockIdx.x;
    const int swz = (bid & 7) * cpx + (bid >> 3);
    const int bm0 = (swz / nbx) << 6;
    const int bn0 = (swz % nbx) << 6;
    const int wm  = (w >> 1) << 5;
    const int wn  = (w & 1) << 5;

    f32x4 acc[2][2] = {};

    const int srow = tid >> 2;
    const int schk = tid & 3;
    const int scol = (schk ^ ((srow >> 1) & 3)) * 8;
    const int sdst = (srow * 4 + schk) * 8;

    auto stage = [&](int buf, int k0) {
        async_copy16(&sA[buf][sdst], &A[(size_t)(bm0 + srow) * K + k0 + scol]);
        async_copy16(&sB[buf][sdst], &Bm[(size_t)(bn0 + srow) * K + k0 + scol]);
    };

    const int NT = K >> 5;
    stage(0, 0);
    stage(1, 32);

    int cons = 0;
    for (int t = 0; t < NT; ++t) {
        if (t + 1 < NT) { VMW(2); } else { VMW(0); }
        __builtin_amdgcn_sched_barrier(0);
        __builtin_amdgcn_s_barrier();
        if (t + 2 < NT) {
            int fill = cons + 2; if (fill >= 3) fill -= 3;
            stage(fill, (t + 2) * 32);
        }
        const __bf16* cA = sA[cons];
        const __bf16* cB = sB[cons];
        bf16x8 af[2], bfr[2];
        #pragma unroll
        for (int m = 0; m < 2; ++m) {
            int r = wm + m * 16 + c;
            af[m] = *(const bf16x8*)&cA[r * 32 + ((g ^ ((r >> 1) & 3)) * 8)];
        }
        #pragma unroll
        for (int n = 0; n < 2; ++n) {
            int r = wn + n * 16 + c;
            bfr[n] = *(const bf16x8*)&cB[r * 32 + ((g ^ ((r >> 1) & 3)) * 8)];
        }
        __builtin_amdgcn_s_setprio(1);
        #pragma unroll
        for (int m = 0; m < 2; ++m)
            #pragma unroll
            for (int n = 0; n < 2; ++n)
                acc[m][n] = mfma16(af[m], bfr[n], acc[m][n]);
        __builtin_amdgcn_s_setprio(0);
        cons = (cons + 1 == 3) ? 0 : cons + 1;
    }

    #pragma unroll
    for (int m = 0; m < 2; ++m) {
        int rr = bm0 + wm + m * 16 + g * 4;
        #pragma unroll
        for (int n = 0; n < 2; ++n) {
            int cc = bn0 + wn + n * 16 + c;
            float bv = bias[cc];
            #pragma unroll
            for (int r2 = 0; r2 < 4; ++r2)
                Cv[(size_t)(rr + r2) * N + cc] = acc[m][n][r2] + bv;
        }
    }
}

// ---------------- banded flash attention, KVBLK=32, K/V dbuf ---------------
// Last tile ends at j_end = q0+32 so keys q0+32..q0+63 reach the upper
// query rows; mask zeroes out-of-band entries. LDS ~26KB -> one dispatch
// round for all 1024 blocks.
__global__ __launch_bounds__(256) void attn_k(const __bf16* __restrict__ qkv,
                                              __bf16* __restrict__ y)
{
    __shared__ __align__(16) unsigned short Ks[2][32 * 72];
    __shared__ __align__(16) unsigned short Vs[2][4 * 528];
    __shared__ __align__(16) unsigned short Ps[64 * 72];

    const int tid  = threadIdx.x;
    const int lane = tid & 63;
    const int w    = tid >> 6;
    const int c    = lane & 15;
    const int g    = lane >> 4;

    const int bid = blockIdx.x;
    const int swz = (bid & 7) * 128 + (bid >> 3);
    const int q0 = (swz & 31) * 64;
    const int hb = swz >> 5;
    const int h  = hb & 15;
    const int b  = hb >> 4;

    bf16x8 qa[2];
    {
        const int qrow = q0 + w * 16 + c;
        const __bf16* qp = qkv + (size_t)(b * T_ + qrow) * 3072 + h * 64 + g * 8;
        bf16x8 r0 = *(const bf16x8*)qp;
        bf16x8 r1 = *(const bf16x8*)(qp + 32);
        #pragma unroll
        for (int e = 0; e < 8; ++e) {
            qa[0][e] = (__bf16)((float)r0[e] * 0.125f);
            qa[1][e] = (__bf16)((float)r1[e] * 0.125f);
        }
    }

    float m_run[4] = {-1e30f, -1e30f, -1e30f, -1e30f};
    float l_run[4] = {0.f, 0.f, 0.f, 0.f};
    f32x4 o[4] = {};

    unsigned vs_lane;
    {
        auto* p3 = (__attribute__((address_space(3))) const unsigned short*)&Vs[0][0];
        vs_lane = (unsigned)(unsigned long long)p3 + (unsigned)(g * 256 + c * 8);
    }

    const int rs = tid >> 3, d8 = (tid & 7) * 8;
    const size_t kbase = (size_t)(b * T_) * 3072 + 1024 + h * 64;

    const int j_start = (q0 >= WIN_) ? (q0 - WIN_) : 0;
    const int j_end   = q0 + 32;

    u16x8 kr, vr;
    {
        const __bf16* p0 = qkv + kbase + (size_t)(j_start + rs) * 3072 + d8;
        kr = *(const u16x8*)p0;  vr = *(const u16x8*)(p0 + 1024);
    }

    int cur = 0;
    for (int j0 = j_start; j0 <= j_end; j0 += 32) {
        *(u16x8*)&Ks[cur][rs * 72 + d8] = kr;
        *(u16x8*)&Vs[cur][(d8 >> 4) * 528 + rs * 16 + (d8 & 15)] = vr;
        __syncthreads();

        if (j0 + 32 <= j_end) {
            const __bf16* p0 = qkv + kbase + (size_t)(j0 + 32 + rs) * 3072 + d8;
            kr = *(const u16x8*)p0;  vr = *(const u16x8*)(p0 + 1024);
        }

        f32x4 sc[2];
        __builtin_amdgcn_s_setprio(1);
        #pragma unroll
        for (int nt = 0; nt < 2; ++nt) {
            const bf16x8 b0 = *(const bf16x8*)&Ks[cur][(nt * 16 + c) * 72 + g * 8];
            const bf16x8 b1 = *(const bf16x8*)&Ks[cur][(nt * 16 + c) * 72 + 32 + g * 8];
            f32x4 s = {0.f, 0.f, 0.f, 0.f};
            s = mfma16(qa[0], b0, s);
            s = mfma16(qa[1], b1, s);
            sc[nt] = s;
        }
        __builtin_amdgcn_s_setprio(0);

        const int rlo = q0 + w * 16;
        const bool need_mask = (j0 + 31 > rlo) || (rlo + 15 - j0 > WIN_);
        if (need_mask) {
            #pragma unroll
            for (int reg = 0; reg < 4; ++reg) {
                const int i_abs = rlo + g * 4 + reg;
                #pragma unroll
                for (int nt = 0; nt < 2; ++nt) {
                    int j_abs = j0 + nt * 16 + c;
                    bool ok = (j_abs <= i_abs) && (i_abs - j_abs <= WIN_);
                    sc[nt][reg] = ok ? sc[nt][reg] : -1e30f;
                }
            }
        }

        float pmax[4];
        #pragma unroll
        for (int reg = 0; reg < 4; ++reg) {
            float bm = fmaxf(sc[0][reg], sc[1][reg]);
            #pragma unroll
            for (int off = 1; off < 16; off <<= 1)
                bm = fmaxf(bm, __shfl_xor(bm, off));
            pmax[reg] = bm;
        }
        int need = 0;
        #pragma unroll
        for (int reg = 0; reg < 4; ++reg)
            need |= (pmax[reg] > m_run[reg] + 8.f) ? 1 : 0;
        if (__any(need)) {
            #pragma unroll
            for (int reg = 0; reg < 4; ++reg) {
                float mn = fmaxf(m_run[reg], pmax[reg]);
                float corr = __expf(m_run[reg] - mn);
                m_run[reg] = mn;
                l_run[reg] *= corr;
                #pragma unroll
                for (int dt = 0; dt < 4; ++dt) o[dt][reg] *= corr;
            }
        }
        #pragma unroll
        for (int reg = 0; reg < 4; ++reg) {
            #pragma unroll
            for (int nt = 0; nt < 2; ++nt) {
                float p = __expf(sc[nt][reg] - m_run[reg]);
                l_run[reg] += p;
                Ps[(w * 16 + g * 4 + reg) * 72 + nt * 16 + c] = f2b(p);
            }
        }

        const bf16x8 pa = *(const bf16x8*)&Ps[(w * 16 + c) * 72 + g * 8];
        u32x2 t0[4], t1[4];
        #pragma unroll
        for (int dt = 0; dt < 4; ++dt) {
            unsigned va = vs_lane + (unsigned)cur * 4224u + dt * 1056u;
            TR16(t0[dt], va, "0");
            TR16(t1[dt], va, "128");
        }
        asm volatile("s_waitcnt lgkmcnt(0)" ::: "memory");
        __builtin_amdgcn_sched_barrier(0);
        __builtin_amdgcn_s_setprio(1);
        #pragma unroll
        for (int dt = 0; dt < 4; ++dt) {
            bf16x8 vb = combine_tr(t0[dt], t1[dt]);
            o[dt] = mfma16(pa, vb, o[dt]);
        }
        __builtin_amdgcn_s_setprio(0);
        cur ^= 1;
    }

    float inv_l[4];
    #pragma unroll
    for (int reg = 0; reg < 4; ++reg) {
        float L = l_run[reg];
        #pragma unroll
        for (int off = 1; off < 16; off <<= 1)
            L += __shfl_xor(L, off);
        inv_l[reg] = 1.f / L;
    }
    #pragma unroll
    for (int dt = 0; dt < 4; ++dt)
        #pragma unroll
        for (int reg = 0; reg < 4; ++reg) {
            size_t row = (size_t)(b * T_ + q0 + w * 16 + g * 4 + reg);
            y[row * 1024 + h * 64 + dt * 16 + c] = (__bf16)(o[dt][reg] * inv_l[reg]);
        }
}

// ---------------- launch ----------------
extern "C" void kernel_launch(void* const* d_in, const int* in_sizes, int n_in,
                              void* d_out, int out_size, void* d_ws, size_t ws_size,
                              hipStream_t stream) {
    const float* x     = (const float*)d_in[0];
    const float* Wqkv  = (const float*)d_in[1];
    const float* Wproj = (const float*)d_in[2];
    const float* bproj = (const float*)d_in[3];
    float* out = (float*)d_out;

    char* p = (char*)d_ws;
    float*  cosT   = (float*)p;   p += (size_t)T_ * 32 * 4;
    float*  sinT   = (float*)p;   p += (size_t)T_ * 32 * 4;
    __bf16* xb     = (__bf16*)p;  p += (size_t)BT_ * 1024 * 2;
    __bf16* Wqkvb  = (__bf16*)p;  p += (size_t)3072 * 1024 * 2;
    __bf16* Wprojb = (__bf16*)p;  p += (size_t)1024 * 1024 * 2;
    __bf16* qkvb   = (__bf16*)p;  p += (size_t)BT_ * 3072 * 2;
    __bf16* yb     = (__bf16*)p;  p += (size_t)BT_ * 1024 * 2;

    const int nprep = (BT_ * 1024 + 3072 * 1024 + 1024 * 1024) / 8 + T_ * 32 / 8;
    prep_k<<<(nprep + 255) / 256, 256, 0, stream>>>(
        x, Wqkv, Wproj, xb, Wqkvb, Wprojb, cosT, sinT);

    gemm_qkv_rope<<<(BT_ / 128) * (3072 / 128), 256, 0, stream>>>(
        xb, Wqkvb, qkvb, BT_, 3072, 1024, cosT, sinT);

    attn_k<<<(T_ / 64) * H_ * B_, 256, 0, stream>>>(qkvb, yb);

    gemm64_proj<<<(BT_ / 64) * (1024 / 64), 256, 0, stream>>>(
        yb, Wprojb, bproj, out, BT_, 1024, 1024);
}